// Round 3
// baseline (1733.620 us; speedup 1.0000x reference)
//
#include <hip/hip_runtime.h>

#define DF 64

// ================= CSR build =================

// count + weighted degree per destination
__global__ void hist_deg(const int* __restrict__ ei, const float* __restrict__ w,
                         int* __restrict__ cnt, float* __restrict__ deg, int E) {
  int e = blockIdx.x * blockDim.x + threadIdx.x;
  if (e >= E) return;
  int d = ei[E + e];
  atomicAdd(&cnt[d], 1);
  unsafeAtomicAdd(&deg[d], w[e]);
}

__global__ void dinv_kernel(float* __restrict__ deg, int n) {
  int i = blockIdx.x * blockDim.x + threadIdx.x;
  if (i < n) deg[i] = rsqrtf(deg[i] + 1.0f);  // self-loop weight 1 folded in
}

// block-local exclusive scan of counts (1024 elems/block), emit block sums
__global__ __launch_bounds__(256) void scan1(const int* __restrict__ cnt,
                                             int* __restrict__ ptr,
                                             int* __restrict__ bsum, int n) {
  __shared__ int lds[256];
  int base = blockIdx.x * 1024 + threadIdx.x * 4;
  int c[4], s = 0;
#pragma unroll
  for (int j = 0; j < 4; j++) {
    int idx = base + j;
    c[j] = idx < n ? cnt[idx] : 0;
    s += c[j];
  }
  int v = s;
  lds[threadIdx.x] = v;
  __syncthreads();
  for (int off = 1; off < 256; off <<= 1) {
    int o = threadIdx.x >= off ? lds[threadIdx.x - off] : 0;
    __syncthreads();
    v += o;
    lds[threadIdx.x] = v;
    __syncthreads();
  }
  int run = v - s;  // exclusive prefix within block
#pragma unroll
  for (int j = 0; j < 4; j++) {
    int idx = base + j;
    if (idx < n) ptr[idx] = run;
    run += c[j];
  }
  if (threadIdx.x == 255) bsum[blockIdx.x] = v;  // block total
}

// exclusive scan of block sums (single block, nb <= 128)
__global__ void scan2(int* __restrict__ bsum, int nb) {
  __shared__ int lds[128];
  int tid = threadIdx.x;
  int sv = tid < nb ? bsum[tid] : 0;
  int v = sv;
  lds[tid] = v;
  __syncthreads();
  for (int off = 1; off < 128; off <<= 1) {
    int o = tid >= off ? lds[tid - off] : 0;
    __syncthreads();
    v += o;
    lds[tid] = v;
    __syncthreads();
  }
  if (tid < nb) bsum[tid] = v - sv;  // exclusive
}

__global__ void scan3(int* __restrict__ ptr, const int* __restrict__ bsum, int n, int E) {
  int i = blockIdx.x * blockDim.x + threadIdx.x;
  if (i < n) ptr[i] += bsum[i >> 10];
  if (i == 0) ptr[n] = E;
}

// scatter edges into CSR slots; val = dinv[src]*w*dinv[dst] (reused both layers)
__global__ void fill_kernel(const int* __restrict__ ei, const float* __restrict__ w,
                            const float* __restrict__ dinv, int* __restrict__ cursor,
                            int* __restrict__ col, float* __restrict__ val, int E) {
  int e = blockIdx.x * blockDim.x + threadIdx.x;
  if (e >= E) return;
  int s = ei[e], d = ei[E + e];
  int pos = atomicAdd(&cursor[d], 1);
  col[pos] = s;
  val[pos] = dinv[s] * w[e] * dinv[d];
}

// ================= compute =================

// xl = A @ W  (wave per row, W in LDS, shfl row-broadcast)
__global__ __launch_bounds__(256) void gemm_valu(const float* __restrict__ A,
                                                 const float* __restrict__ W,
                                                 float* __restrict__ out, int n) {
  __shared__ float Wl[DF * DF];
  for (int t = threadIdx.x; t < DF * DF; t += 256) Wl[t] = W[t];
  __syncthreads();
  int f = threadIdx.x & 63;
  int sub = threadIdx.x >> 6;
  for (int i = blockIdx.x * 4 + sub; i < n; i += gridDim.x * 4) {
    float xv = A[(size_t)i * DF + f];
    float acc = 0.f;
#pragma unroll
    for (int k = 0; k < DF; k++) acc += __shfl(xv, k, 64) * Wl[k * DF + f];
    out[(size_t)i * DF + f] = acc;
  }
}

// xl2 = BN_PReLU(acc1) @ W  — BN1 fused into A-load (saves a full pass)
__global__ __launch_bounds__(256) void gemm_bn(const float* __restrict__ acc,
                                               const float* __restrict__ stats,
                                               const float* __restrict__ alpha_p,
                                               const float* __restrict__ W,
                                               float* __restrict__ out, int n) {
  __shared__ float Wl[DF * DF];
  for (int t = threadIdx.x; t < DF * DF; t += 256) Wl[t] = W[t];
  __syncthreads();
  int f = threadIdx.x & 63;
  int sub = threadIdx.x >> 6;
  float s = stats[128 + f], t0 = stats[192 + f], a = alpha_p[0];
  for (int i = blockIdx.x * 4 + sub; i < n; i += gridDim.x * 4) {
    float y = acc[(size_t)i * DF + f] * s + t0;
    y = (y >= 0.f) ? y : a * y;
    float r = 0.f;
#pragma unroll
    for (int k = 0; k < DF; k++) r += __shfl(y, k, 64) * Wl[k * DF + f];
    out[(size_t)i * DF + f] = r;
  }
}

// gather-form aggregation: wave per node; self-loop + bias init; BN stats fused
__global__ __launch_bounds__(256) void aggregate(const int* __restrict__ ptr,
                                                 const int* __restrict__ col,
                                                 const float* __restrict__ val,
                                                 const float* __restrict__ xl,
                                                 const float* __restrict__ dinv,
                                                 const float* __restrict__ bias,
                                                 float* __restrict__ outacc,
                                                 float* __restrict__ stats, int n) {
  int f = threadIdx.x & 63;
  int sub = threadIdx.x >> 6;
  int i = blockIdx.x * 4 + sub;
  float s_sum = 0.f, s_sq = 0.f;
  if (i < n) {
    float di = dinv[i];
    float acc = xl[(size_t)i * DF + f] * di * di + bias[f];
    int e = ptr[i], e1 = ptr[i + 1];
    for (; e + 4 <= e1; e += 4) {
      int c0 = col[e], c1 = col[e + 1], c2 = col[e + 2], c3 = col[e + 3];
      float v0 = val[e], v1 = val[e + 1], v2 = val[e + 2], v3 = val[e + 3];
      float x0 = xl[(size_t)c0 * DF + f];
      float x1 = xl[(size_t)c1 * DF + f];
      float x2 = xl[(size_t)c2 * DF + f];
      float x3 = xl[(size_t)c3 * DF + f];
      acc += v0 * x0 + v1 * x1 + v2 * x2 + v3 * x3;
    }
    for (; e < e1; e++) acc += val[e] * xl[(size_t)col[e] * DF + f];
    outacc[(size_t)i * DF + f] = acc;
    s_sum = acc;
    s_sq = acc * acc;
  }
  __shared__ float ls[4][DF], lss[4][DF];
  ls[sub][f] = s_sum;
  lss[sub][f] = s_sq;
  __syncthreads();
  if (threadIdx.x < DF) {
    float t1 = ls[0][f] + ls[1][f] + ls[2][f] + ls[3][f];
    float t2 = lss[0][f] + lss[1][f] + lss[2][f] + lss[3][f];
    unsafeAtomicAdd(&stats[f], t1);
    unsafeAtomicAdd(&stats[DF + f], t2);
  }
}

__global__ void finalize_stats(float* __restrict__ stats, const float* __restrict__ gamma,
                               const float* __restrict__ beta, int n) {
  int f = threadIdx.x;
  if (f >= DF) return;
  float mean = stats[f] / n;
  float var = stats[DF + f] / n - mean * mean;
  float rstd = rsqrtf(var + 1e-5f);
  float s = gamma[f] * rstd;
  stats[128 + f] = s;
  stats[192 + f] = beta[f] - mean * s;
}

__global__ void bnapply(const float* __restrict__ acc, const float* __restrict__ stats,
                        const float* __restrict__ alpha_p, float* __restrict__ outb, int n) {
  int i = blockIdx.x * 4 + (threadIdx.x >> 6);
  if (i >= n) return;
  int f = threadIdx.x & 63;
  float y = acc[(size_t)i * DF + f] * stats[128 + f] + stats[192 + f];
  float a = alpha_p[0];
  y = (y >= 0.f) ? y : a * y;
  outb[(size_t)i * DF + f] = y;
}

extern "C" void kernel_launch(void* const* d_in, const int* in_sizes, int n_in,
                              void* d_out, int out_size, void* d_ws, size_t ws_size,
                              hipStream_t stream) {
  const float* x  = (const float*)d_in[0];
  const int* ei   = (const int*)d_in[1];
  const float* w  = (const float*)d_in[2];
  const float* W1 = (const float*)d_in[3];
  const float* b1 = (const float*)d_in[4];
  const float* g1 = (const float*)d_in[5];
  const float* be1= (const float*)d_in[6];
  const float* al1= (const float*)d_in[7];
  const float* W2 = (const float*)d_in[8];
  const float* b2 = (const float*)d_in[9];
  const float* g2 = (const float*)d_in[10];
  const float* be2= (const float*)d_in[11];
  const float* al2= (const float*)d_in[12];
  float* out = (float*)d_out;

  const int n = in_sizes[0] / DF;
  const int E = in_sizes[2];
  const size_t na = ((size_t)n + 255) & ~(size_t)255;  // padded n

  // ---- workspace layout (all 4-byte elems) ----
  char* base = (char*)d_ws;
  float* deg    = (float*)base;                          // na
  int*   cnt    = (int*)(deg + na);                      // na
  float* stats1 = (float*)(cnt + na);                    // 256
  float* stats2 = stats1 + 256;                          // 256
  int*   ptr    = (int*)(stats2 + 256);                  // na+64
  int*   bsum   = ptr + na + 64;                         // 128
  int*   cursor = bsum + 128;                            // na
  int*   col    = cursor + na;                           // E
  float* val    = (float*)(col + E);                     // E
  float* R1     = val + E;                               // na*64
  float* R2     = R1 + na * DF;                          // na*64

  const int nb_nodes = (n + 3) / 4;
  const int nb_e256  = (E + 255) / 256;
  const int nb_scan1 = (n + 1023) / 1024;   // <=128 blocks for n<=131072
  const int nb_gemm  = 2048;

  // zero: deg, cnt, stats1, stats2 (contiguous)
  hipMemsetAsync(deg, 0, (2 * na + 512) * sizeof(float), stream);

  // ---- CSR build ----
  hist_deg<<<nb_e256, 256, 0, stream>>>(ei, w, cnt, deg, E);
  dinv_kernel<<<(n + 255) / 256, 256, 0, stream>>>(deg, n);
  scan1<<<nb_scan1, 256, 0, stream>>>(cnt, ptr, bsum, n);
  scan2<<<1, 128, 0, stream>>>(bsum, nb_scan1);
  scan3<<<(n + 255) / 256, 256, 0, stream>>>(ptr, bsum, n, E);
  hipMemcpyAsync(cursor, ptr, (size_t)n * sizeof(int), hipMemcpyDeviceToDevice, stream);
  fill_kernel<<<nb_e256, 256, 0, stream>>>(ei, w, deg, cursor, col, val, E);

  // ---- layer 1 ----
  gemm_valu<<<nb_gemm, 256, 0, stream>>>(x, W1, R1, n);                       // xl1 -> R1
  aggregate<<<nb_nodes, 256, 0, stream>>>(ptr, col, val, R1, deg, b1, R2, stats1, n); // acc1 -> R2 (+stats)
  finalize_stats<<<1, 64, 0, stream>>>(stats1, g1, be1, n);

  // ---- layer 2 (BN1+PReLU fused into gemm A-load) ----
  gemm_bn<<<nb_gemm, 256, 0, stream>>>(R2, stats1, al1, W2, R1, n);           // xl2 -> R1
  aggregate<<<nb_nodes, 256, 0, stream>>>(ptr, col, val, R1, deg, b2, R2, stats2, n); // acc2 -> R2 (+stats)
  finalize_stats<<<1, 64, 0, stream>>>(stats2, g2, be2, n);
  bnapply<<<nb_nodes, 256, 0, stream>>>(R2, stats2, al2, out, n);
}

// Round 4
// 673.706 us; speedup vs baseline: 2.5733x; 2.5733x over previous
//
#include <hip/hip_runtime.h>

#define DF 64

// ================= CSR build =================

__global__ void hist_deg(const int* __restrict__ ei, const float* __restrict__ w,
                         int* __restrict__ cnt, float* __restrict__ deg, int E) {
  int e = blockIdx.x * blockDim.x + threadIdx.x;
  if (e >= E) return;
  int d = ei[E + e];
  atomicAdd(&cnt[d], 1);
  unsafeAtomicAdd(&deg[d], w[e]);
}

__global__ void dinv_kernel(float* __restrict__ deg, int n) {
  int i = blockIdx.x * blockDim.x + threadIdx.x;
  if (i < n) deg[i] = rsqrtf(deg[i] + 1.0f);  // self-loop weight 1 folded in
}

// block-local exclusive scan of counts (1024/block) -> cursor, emit block sums
__global__ __launch_bounds__(256) void scan1(const int* __restrict__ cnt,
                                             int* __restrict__ cursor,
                                             int* __restrict__ bsum, int n) {
  __shared__ int lds[256];
  int base = blockIdx.x * 1024 + threadIdx.x * 4;
  int c[4], s = 0;
#pragma unroll
  for (int j = 0; j < 4; j++) {
    int idx = base + j;
    c[j] = idx < n ? cnt[idx] : 0;
    s += c[j];
  }
  int v = s;
  lds[threadIdx.x] = v;
  __syncthreads();
  for (int off = 1; off < 256; off <<= 1) {
    int o = threadIdx.x >= off ? lds[threadIdx.x - off] : 0;
    __syncthreads();
    v += o;
    lds[threadIdx.x] = v;
    __syncthreads();
  }
  int run = v - s;
#pragma unroll
  for (int j = 0; j < 4; j++) {
    int idx = base + j;
    if (idx < n) cursor[idx] = run;
    run += c[j];
  }
  if (threadIdx.x == 255) bsum[blockIdx.x] = v;
}

__global__ void scan2(int* __restrict__ bsum, int nb) {
  __shared__ int lds[128];
  int tid = threadIdx.x;
  int sv = tid < nb ? bsum[tid] : 0;
  int v = sv;
  lds[tid] = v;
  __syncthreads();
  for (int off = 1; off < 128; off <<= 1) {
    int o = tid >= off ? lds[tid - off] : 0;
    __syncthreads();
    v += o;
    lds[tid] = v;
    __syncthreads();
  }
  if (tid < nb) bsum[tid] = v - sv;
}

__global__ void scan3(int* __restrict__ cursor, const int* __restrict__ bsum, int n) {
  int i = blockIdx.x * blockDim.x + threadIdx.x;
  if (i < n) cursor[i] += bsum[i >> 10];
}

// scatter edges into CSR slots (dst-sorted); val = dinv[s]*w*dinv[d]
__global__ void fill_kernel(const int* __restrict__ ei, const float* __restrict__ w,
                            const float* __restrict__ dinv, int* __restrict__ cursor,
                            int* __restrict__ col, float* __restrict__ val,
                            int* __restrict__ dstid, int E) {
  int e = blockIdx.x * blockDim.x + threadIdx.x;
  if (e >= E) return;
  int s = ei[e], d = ei[E + e];
  int pos = atomicAdd(&cursor[d], 1);
  col[pos] = s;
  val[pos] = dinv[s] * w[e] * dinv[d];
  dstid[pos] = d;
}

// ================= compute =================

// xl = A @ W ; acc = xl*dinv^2 + bias   (init fused into gemm)
__global__ __launch_bounds__(256) void gemm_init(const float* __restrict__ A,
                                                 const float* __restrict__ W,
                                                 const float* __restrict__ bias,
                                                 const float* __restrict__ dinv,
                                                 float* __restrict__ xl,
                                                 float* __restrict__ acc, int n) {
  __shared__ float Wl[DF * DF];
  for (int t = threadIdx.x; t < DF * DF; t += 256) Wl[t] = W[t];
  __syncthreads();
  int f = threadIdx.x & 63;
  int sub = threadIdx.x >> 6;
  float bf = bias[f];
  for (int i = blockIdx.x * 4 + sub; i < n; i += gridDim.x * 4) {
    float xv = A[(size_t)i * DF + f];
    float r = 0.f;
#pragma unroll
    for (int k = 0; k < DF; k++) r += __shfl(xv, k, 64) * Wl[k * DF + f];
    xl[(size_t)i * DF + f] = r;
    float di = dinv[i];
    acc[(size_t)i * DF + f] = r * di * di + bf;
  }
}

// xl2 = BN_PReLU(acc1) @ W ; acc2 = xl2*dinv^2 + bias   (BN + init fused)
__global__ __launch_bounds__(256) void gemm_bn_init(const float* __restrict__ accin,
                                                    const float* __restrict__ stats,
                                                    const float* __restrict__ alpha_p,
                                                    const float* __restrict__ W,
                                                    const float* __restrict__ bias,
                                                    const float* __restrict__ dinv,
                                                    float* __restrict__ xl,
                                                    float* __restrict__ acc, int n) {
  __shared__ float Wl[DF * DF];
  for (int t = threadIdx.x; t < DF * DF; t += 256) Wl[t] = W[t];
  __syncthreads();
  int f = threadIdx.x & 63;
  int sub = threadIdx.x >> 6;
  float s = stats[128 + f], t0 = stats[192 + f], a = alpha_p[0], bf = bias[f];
  for (int i = blockIdx.x * 4 + sub; i < n; i += gridDim.x * 4) {
    float y = accin[(size_t)i * DF + f] * s + t0;
    y = (y >= 0.f) ? y : a * y;
    float r = 0.f;
#pragma unroll
    for (int k = 0; k < DF; k++) r += __shfl(y, k, 64) * Wl[k * DF + f];
    xl[(size_t)i * DF + f] = r;
    float di = dinv[i];
    acc[(size_t)i * DF + f] = r * di * di + bf;
  }
}

// edge-parallel segmented reduction: wave = 64 consecutive dst-sorted edges.
// 3 coalesced lane-loads for (col,val,dst); gathers in batches of 16; one
// fp32 atomic per dst-run (~5 per wave).
__global__ __launch_bounds__(256) void edge_agg(const int* __restrict__ col,
                                                const float* __restrict__ val,
                                                const int* __restrict__ dstid,
                                                const float* __restrict__ xl,
                                                float* __restrict__ acc, int E) {
  int w = blockIdx.x * 4 + (threadIdx.x >> 6);
  int lane = threadIdx.x & 63;
  long e0 = (long)w * 64;
  if (e0 >= E) return;
  long ei = e0 + lane;
  long idx = ei < E ? ei : (long)E - 1;       // clamp; pads contribute 0
  int c = col[idx];
  int d = dstid[idx];
  float v = (ei < E) ? val[idx] : 0.f;
  float a = 0.f;
  int cur = __shfl(d, 0);
#pragma unroll
  for (int base = 0; base < 64; base += 16) {
    float xb[16];
#pragma unroll
    for (int j = 0; j < 16; j++) {
      int cj = __shfl(c, base + j);
      xb[j] = xl[(size_t)cj * DF + lane];     // 16 independent 256B gathers
    }
#pragma unroll
    for (int j = 0; j < 16; j++) {
      int dj = __shfl(d, base + j);
      float vj = __shfl(v, base + j);
      if (dj != cur) {                         // wave-uniform condition
        unsafeAtomicAdd(&acc[(size_t)cur * DF + lane], a);
        a = 0.f;
        cur = dj;
      }
      a = fmaf(vj, xb[j], a);
    }
  }
  unsafeAtomicAdd(&acc[(size_t)cur * DF + lane], a);
}

// per-feature sum / sumsq over nodes
__global__ void stats_kernel(const float* __restrict__ acc, float* __restrict__ stats, int n) {
  int f = threadIdx.x & 63;
  int sub = threadIdx.x >> 6;
  float s = 0.f, ss = 0.f;
  for (int i = blockIdx.x * 4 + sub; i < n; i += gridDim.x * 4) {
    float v = acc[(size_t)i * DF + f];
    s += v;
    ss += v * v;
  }
  __shared__ float ls[4][DF], lss[4][DF];
  ls[sub][f] = s;
  lss[sub][f] = ss;
  __syncthreads();
  if (threadIdx.x < DF) {
    float t1 = ls[0][f] + ls[1][f] + ls[2][f] + ls[3][f];
    float t2 = lss[0][f] + lss[1][f] + lss[2][f] + lss[3][f];
    unsafeAtomicAdd(&stats[f], t1);
    unsafeAtomicAdd(&stats[DF + f], t2);
  }
}

__global__ void finalize_stats(float* __restrict__ stats, const float* __restrict__ gamma,
                               const float* __restrict__ beta, int n) {
  int f = threadIdx.x;
  if (f >= DF) return;
  float mean = stats[f] / n;
  float var = stats[DF + f] / n - mean * mean;
  float rstd = rsqrtf(var + 1e-5f);
  float s = gamma[f] * rstd;
  stats[128 + f] = s;
  stats[192 + f] = beta[f] - mean * s;
}

__global__ void bnapply(const float* __restrict__ acc, const float* __restrict__ stats,
                        const float* __restrict__ alpha_p, float* __restrict__ outb, int n) {
  int i = blockIdx.x * 4 + (threadIdx.x >> 6);
  if (i >= n) return;
  int f = threadIdx.x & 63;
  float y = acc[(size_t)i * DF + f] * stats[128 + f] + stats[192 + f];
  float a = alpha_p[0];
  y = (y >= 0.f) ? y : a * y;
  outb[(size_t)i * DF + f] = y;
}

extern "C" void kernel_launch(void* const* d_in, const int* in_sizes, int n_in,
                              void* d_out, int out_size, void* d_ws, size_t ws_size,
                              hipStream_t stream) {
  const float* x  = (const float*)d_in[0];
  const int* ei   = (const int*)d_in[1];
  const float* w  = (const float*)d_in[2];
  const float* W1 = (const float*)d_in[3];
  const float* b1 = (const float*)d_in[4];
  const float* g1 = (const float*)d_in[5];
  const float* be1= (const float*)d_in[6];
  const float* al1= (const float*)d_in[7];
  const float* W2 = (const float*)d_in[8];
  const float* b2 = (const float*)d_in[9];
  const float* g2 = (const float*)d_in[10];
  const float* be2= (const float*)d_in[11];
  const float* al2= (const float*)d_in[12];
  float* out = (float*)d_out;

  const int n = in_sizes[0] / DF;
  const int E = in_sizes[2];
  const size_t na = ((size_t)n + 255) & ~(size_t)255;

  // ---- workspace layout (4-byte elems) ----
  char* base = (char*)d_ws;
  float* deg    = (float*)base;                 // na
  int*   cnt    = (int*)(deg + na);             // na
  float* stats1 = (float*)(cnt + na);           // 256
  float* stats2 = stats1 + 256;                 // 256
  int*   cursor = (int*)(stats2 + 256);         // na
  int*   bsum   = cursor + na;                  // 128
  int*   col    = bsum + 128;                   // E
  float* val    = (float*)(col + E);            // E
  int*   dstid  = (int*)(val + E);              // E
  float* XL     = (float*)(dstid + E);          // na*64
  float* ACC    = XL + na * DF;                 // na*64

  const int nb_nodes = (n + 3) / 4;
  const int nb_e256  = (E + 255) / 256;
  const int nb_scan1 = (n + 1023) / 1024;       // <=128
  const int nb_gemm  = 2048;
  const int nb_edge  = ((E + 63) / 64 + 3) / 4; // 4 waves/block
  const int nb_stats = 1024;

  // zero: deg, cnt, stats1, stats2 (contiguous)
  hipMemsetAsync(deg, 0, (2 * na + 512) * sizeof(float), stream);

  // ---- CSR build ----
  hist_deg<<<nb_e256, 256, 0, stream>>>(ei, w, cnt, deg, E);
  dinv_kernel<<<(n + 255) / 256, 256, 0, stream>>>(deg, n);
  scan1<<<nb_scan1, 256, 0, stream>>>(cnt, cursor, bsum, n);
  scan2<<<1, 128, 0, stream>>>(bsum, nb_scan1);
  scan3<<<(n + 255) / 256, 256, 0, stream>>>(cursor, bsum, n);
  fill_kernel<<<nb_e256, 256, 0, stream>>>(ei, w, deg, cursor, col, val, dstid, E);

  // ---- layer 1 ----
  gemm_init<<<nb_gemm, 256, 0, stream>>>(x, W1, b1, deg, XL, ACC, n);
  edge_agg<<<nb_edge, 256, 0, stream>>>(col, val, dstid, XL, ACC, E);
  stats_kernel<<<nb_stats, 256, 0, stream>>>(ACC, stats1, n);
  finalize_stats<<<1, 64, 0, stream>>>(stats1, g1, be1, n);

  // ---- layer 2 ----
  gemm_bn_init<<<nb_gemm, 256, 0, stream>>>(ACC, stats1, al1, W2, b2, deg, XL, ACC, n);
  edge_agg<<<nb_edge, 256, 0, stream>>>(col, val, dstid, XL, ACC, E);
  stats_kernel<<<nb_stats, 256, 0, stream>>>(ACC, stats2, n);
  finalize_stats<<<1, 64, 0, stream>>>(stats2, g2, be2, n);
  bnapply<<<nb_nodes, 256, 0, stream>>>(ACC, stats2, al2, out, n);
}

// Round 5
// 657.392 us; speedup vs baseline: 2.6371x; 1.0248x over previous
//
#include <hip/hip_runtime.h>

#define DF 64

// ================= CSR build =================

// count edges per destination (int atomics only — deg comes later, atomic-free)
__global__ void hist(const int* __restrict__ ei, int* __restrict__ cnt, int E) {
  int e = blockIdx.x * blockDim.x + threadIdx.x;
  if (e < E) atomicAdd(&cnt[ei[E + e]], 1);
}

// block-local exclusive scan of counts (1024/block), emit block sums
__global__ __launch_bounds__(256) void scan1(const int* __restrict__ cnt,
                                             int* __restrict__ ptr,
                                             int* __restrict__ bsum, int n) {
  __shared__ int lds[256];
  int base = blockIdx.x * 1024 + threadIdx.x * 4;
  int c[4], s = 0;
#pragma unroll
  for (int j = 0; j < 4; j++) {
    int idx = base + j;
    c[j] = idx < n ? cnt[idx] : 0;
    s += c[j];
  }
  int v = s;
  lds[threadIdx.x] = v;
  __syncthreads();
  for (int off = 1; off < 256; off <<= 1) {
    int o = threadIdx.x >= off ? lds[threadIdx.x - off] : 0;
    __syncthreads();
    v += o;
    lds[threadIdx.x] = v;
    __syncthreads();
  }
  int run = v - s;
#pragma unroll
  for (int j = 0; j < 4; j++) {
    int idx = base + j;
    if (idx < n) ptr[idx] = run;
    run += c[j];
  }
  if (threadIdx.x == 255) bsum[blockIdx.x] = v;
}

__global__ void scan2(int* __restrict__ bsum, int nb) {
  __shared__ int lds[128];
  int tid = threadIdx.x;
  int sv = tid < nb ? bsum[tid] : 0;
  int v = sv;
  lds[tid] = v;
  __syncthreads();
  for (int off = 1; off < 128; off <<= 1) {
    int o = tid >= off ? lds[tid - off] : 0;
    __syncthreads();
    v += o;
    lds[tid] = v;
    __syncthreads();
  }
  if (tid < nb) bsum[tid] = v - sv;
}

// add block offsets; write both ptr (stable starts) and cursor (fill allocator)
__global__ void scan3(int* __restrict__ ptr, int* __restrict__ cursor,
                      const int* __restrict__ bsum, int n, int E) {
  int i = blockIdx.x * blockDim.x + threadIdx.x;
  if (i < n) {
    int p = ptr[i] + bsum[i >> 10];
    ptr[i] = p;
    cursor[i] = p;
  }
  if (i == 0) ptr[n] = E;
}

// scatter edges into dst-sorted CSR slots; single 16B packed store per edge
__global__ void fill_kernel(const int* __restrict__ ei, const float* __restrict__ w,
                            int* __restrict__ cursor, int4* __restrict__ pk, int E) {
  int e = blockIdx.x * blockDim.x + threadIdx.x;
  if (e >= E) return;
  int s = ei[e], d = ei[E + e];
  int pos = atomicAdd(&cursor[d], 1);
  pk[pos] = make_int4(s, d, __float_as_int(w[e]), 0);
}

// atomic-free weighted degree from sorted CSR + fused rsqrt (self-loop +1)
__global__ void degsum(const int* __restrict__ ptr, const int4* __restrict__ pk,
                       float* __restrict__ dinv, int n) {
  int i = blockIdx.x * blockDim.x + threadIdx.x;
  if (i >= n) return;
  int e0 = ptr[i], e1 = ptr[i + 1];
  float s = 0.f;
  for (int e = e0; e < e1; e++) s += __int_as_float(pk[e].z);
  dinv[i] = rsqrtf(s + 1.0f);
}

// val[e] = w * dinv[src] * dinv[dst]  (dinv is 400KB, L2-resident gathers)
__global__ void scale_kernel(const int4* __restrict__ pk, const float* __restrict__ dinv,
                             float* __restrict__ val, int E) {
  int e = blockIdx.x * blockDim.x + threadIdx.x;
  if (e >= E) return;
  int4 p = pk[e];
  val[e] = __int_as_float(p.z) * dinv[p.x] * dinv[p.y];
}

// ================= compute =================

// xl = A @ W ; acc = xl*dinv^2 + bias   (self-loop init fused)
__global__ __launch_bounds__(256) void gemm_init(const float* __restrict__ A,
                                                 const float* __restrict__ W,
                                                 const float* __restrict__ bias,
                                                 const float* __restrict__ dinv,
                                                 float* __restrict__ xl,
                                                 float* __restrict__ acc, int n) {
  __shared__ float Wl[DF * DF];
  for (int t = threadIdx.x; t < DF * DF; t += 256) Wl[t] = W[t];
  __syncthreads();
  int f = threadIdx.x & 63;
  int sub = threadIdx.x >> 6;
  float bf = bias[f];
  for (int i = blockIdx.x * 4 + sub; i < n; i += gridDim.x * 4) {
    float xv = A[(size_t)i * DF + f];
    float r = 0.f;
#pragma unroll
    for (int k = 0; k < DF; k++) r += __shfl(xv, k, 64) * Wl[k * DF + f];
    xl[(size_t)i * DF + f] = r;
    float di = dinv[i];
    acc[(size_t)i * DF + f] = r * di * di + bf;
  }
}

// xl2 = BN_PReLU(acc1) @ W ; acc2 = xl2*dinv^2 + bias
__global__ __launch_bounds__(256) void gemm_bn_init(const float* __restrict__ accin,
                                                    const float* __restrict__ stats,
                                                    const float* __restrict__ alpha_p,
                                                    const float* __restrict__ W,
                                                    const float* __restrict__ bias,
                                                    const float* __restrict__ dinv,
                                                    float* __restrict__ xl,
                                                    float* __restrict__ acc, int n) {
  __shared__ float Wl[DF * DF];
  for (int t = threadIdx.x; t < DF * DF; t += 256) Wl[t] = W[t];
  __syncthreads();
  int f = threadIdx.x & 63;
  int sub = threadIdx.x >> 6;
  float s = stats[128 + f], t0 = stats[192 + f], a = alpha_p[0], bf = bias[f];
  for (int i = blockIdx.x * 4 + sub; i < n; i += gridDim.x * 4) {
    float y = accin[(size_t)i * DF + f] * s + t0;
    y = (y >= 0.f) ? y : a * y;
    float r = 0.f;
#pragma unroll
    for (int k = 0; k < DF; k++) r += __shfl(y, k, 64) * Wl[k * DF + f];
    xl[(size_t)i * DF + f] = r;
    float di = dinv[i];
    acc[(size_t)i * DF + f] = r * di * di + bf;
  }
}

// edge-parallel segmented reduction over dst-sorted CSR (wave = 64 edges)
__global__ __launch_bounds__(256) void edge_agg(const int4* __restrict__ pk,
                                                const float* __restrict__ val,
                                                const float* __restrict__ xl,
                                                float* __restrict__ acc, int E) {
  int w = blockIdx.x * 4 + (threadIdx.x >> 6);
  int lane = threadIdx.x & 63;
  long e0 = (long)w * 64;
  if (e0 >= E) return;
  long ei = e0 + lane;
  long idx = ei < E ? ei : (long)E - 1;
  int4 p = pk[idx];
  int c = p.x, d = p.y;
  float v = (ei < E) ? val[idx] : 0.f;
  float a = 0.f;
  int cur = __shfl(d, 0);
#pragma unroll
  for (int base = 0; base < 64; base += 16) {
    float xb[16];
#pragma unroll
    for (int j = 0; j < 16; j++) {
      int cj = __shfl(c, base + j);
      xb[j] = xl[(size_t)cj * DF + lane];  // 16 independent 256B gathers
    }
#pragma unroll
    for (int j = 0; j < 16; j++) {
      int dj = __shfl(d, base + j);
      float vj = __shfl(v, base + j);
      if (dj != cur) {                      // wave-uniform
        unsafeAtomicAdd(&acc[(size_t)cur * DF + lane], a);
        a = 0.f;
        cur = dj;
      }
      a = fmaf(vj, xb[j], a);
    }
  }
  unsafeAtomicAdd(&acc[(size_t)cur * DF + lane], a);
}

// per-feature sum / sumsq over nodes
__global__ void stats_kernel(const float* __restrict__ acc, float* __restrict__ stats, int n) {
  int f = threadIdx.x & 63;
  int sub = threadIdx.x >> 6;
  float s = 0.f, ss = 0.f;
  for (int i = blockIdx.x * 4 + sub; i < n; i += gridDim.x * 4) {
    float v = acc[(size_t)i * DF + f];
    s += v;
    ss += v * v;
  }
  __shared__ float ls[4][DF], lss[4][DF];
  ls[sub][f] = s;
  lss[sub][f] = ss;
  __syncthreads();
  if (threadIdx.x < DF) {
    float t1 = ls[0][f] + ls[1][f] + ls[2][f] + ls[3][f];
    float t2 = lss[0][f] + lss[1][f] + lss[2][f] + lss[3][f];
    unsafeAtomicAdd(&stats[f], t1);
    unsafeAtomicAdd(&stats[DF + f], t2);
  }
}

__global__ void finalize_stats(float* __restrict__ stats, const float* __restrict__ gamma,
                               const float* __restrict__ beta, int n) {
  int f = threadIdx.x;
  if (f >= DF) return;
  float mean = stats[f] / n;
  float var = stats[DF + f] / n - mean * mean;
  float rstd = rsqrtf(var + 1e-5f);
  float s = gamma[f] * rstd;
  stats[128 + f] = s;
  stats[192 + f] = beta[f] - mean * s;
}

__global__ void bnapply(const float* __restrict__ acc, const float* __restrict__ stats,
                        const float* __restrict__ alpha_p, float* __restrict__ outb, int n) {
  int i = blockIdx.x * 4 + (threadIdx.x >> 6);
  if (i >= n) return;
  int f = threadIdx.x & 63;
  float y = acc[(size_t)i * DF + f] * stats[128 + f] + stats[192 + f];
  float a = alpha_p[0];
  y = (y >= 0.f) ? y : a * y;
  outb[(size_t)i * DF + f] = y;
}

extern "C" void kernel_launch(void* const* d_in, const int* in_sizes, int n_in,
                              void* d_out, int out_size, void* d_ws, size_t ws_size,
                              hipStream_t stream) {
  const float* x  = (const float*)d_in[0];
  const int* ei   = (const int*)d_in[1];
  const float* w  = (const float*)d_in[2];
  const float* W1 = (const float*)d_in[3];
  const float* b1 = (const float*)d_in[4];
  const float* g1 = (const float*)d_in[5];
  const float* be1= (const float*)d_in[6];
  const float* al1= (const float*)d_in[7];
  const float* W2 = (const float*)d_in[8];
  const float* b2 = (const float*)d_in[9];
  const float* g2 = (const float*)d_in[10];
  const float* be2= (const float*)d_in[11];
  const float* al2= (const float*)d_in[12];
  float* out = (float*)d_out;

  const int n = in_sizes[0] / DF;
  const int E = in_sizes[2];
  const size_t na = ((size_t)n + 255) & ~(size_t)255;

  // ---- workspace layout (4-byte elems; pk 16B-aligned since all counts %4==0) ----
  char* base = (char*)d_ws;
  float* dinv   = (float*)base;                 // na
  int*   cnt    = (int*)(dinv + na);            // na
  float* stats1 = (float*)(cnt + na);           // 256
  float* stats2 = stats1 + 256;                 // 256
  int*   ptr    = (int*)(stats2 + 256);         // na+64
  int*   cursor = ptr + na + 64;                // na
  int*   bsum   = cursor + na;                  // 128
  int*   pad    = bsum + 128;                   // 64 (align to 16B boundary)
  int4*  pk     = (int4*)(pad + 64);            // E   (16B each)
  float* val    = (float*)(pk + E);             // E
  float* XL     = val + E;                      // na*64
  float* ACC    = XL + na * DF;                 // na*64

  const int nb_nodes = (n + 3) / 4;
  const int nb_e256  = (E + 255) / 256;
  const int nb_scan1 = (n + 1023) / 1024;       // <=128
  const int nb_gemm  = 2048;
  const int nb_edge  = ((E + 63) / 64 + 3) / 4; // 4 waves/block
  const int nb_stats = 1024;

  // zero: cnt, stats1, stats2 (contiguous); dinv/ptr/cursor are fully overwritten
  hipMemsetAsync(cnt, 0, (na + 512) * sizeof(float), stream);

  // ---- CSR build ----
  hist<<<nb_e256, 256, 0, stream>>>(ei, cnt, E);
  scan1<<<nb_scan1, 256, 0, stream>>>(cnt, ptr, bsum, n);
  scan2<<<1, 128, 0, stream>>>(bsum, nb_scan1);
  scan3<<<(n + 255) / 256, 256, 0, stream>>>(ptr, cursor, bsum, n, E);
  fill_kernel<<<nb_e256, 256, 0, stream>>>(ei, w, cursor, pk, E);
  degsum<<<(n + 255) / 256, 256, 0, stream>>>(ptr, pk, dinv, n);
  scale_kernel<<<nb_e256, 256, 0, stream>>>(pk, dinv, val, E);

  // ---- layer 1 ----
  gemm_init<<<nb_gemm, 256, 0, stream>>>(x, W1, b1, dinv, XL, ACC, n);
  edge_agg<<<nb_edge, 256, 0, stream>>>(pk, val, XL, ACC, E);
  stats_kernel<<<nb_stats, 256, 0, stream>>>(ACC, stats1, n);
  finalize_stats<<<1, 64, 0, stream>>>(stats1, g1, be1, n);

  // ---- layer 2 ----
  gemm_bn_init<<<nb_gemm, 256, 0, stream>>>(ACC, stats1, al1, W2, b2, dinv, XL, ACC, n);
  edge_agg<<<nb_edge, 256, 0, stream>>>(pk, val, XL, ACC, E);
  stats_kernel<<<nb_stats, 256, 0, stream>>>(ACC, stats2, n);
  finalize_stats<<<1, 64, 0, stream>>>(stats2, g2, be2, n);
  bnapply<<<nb_nodes, 256, 0, stream>>>(ACC, stats2, al2, out, n);
}

// Round 6
// 519.186 us; speedup vs baseline: 3.3391x; 1.2662x over previous
//
#include <hip/hip_runtime.h>

#define DF 64
#define BSH 8              // bucket = dst >> 8  (256 dst per bucket)
#define BW  256

typedef unsigned short u16;
typedef unsigned int u32;

__device__ __forceinline__ float bf2f(u16 u) { return __uint_as_float(((u32)u) << 16); }
__device__ __forceinline__ u16 f2bf(float f) {
  u32 v = __float_as_uint(f);
  return (u16)((v + 0x7FFFu + ((v >> 16) & 1u)) >> 16);
}

// ============== bucket-sort CSR build (atomic-free globals) ==============

// per-block histogram of dst-buckets -> gh[b][c]  (no global atomics)
__global__ __launch_bounds__(256) void prehist(const int* __restrict__ ei,
                                               int* __restrict__ gh, int E, int NB) {
  __shared__ int lh[512];
  for (int t = threadIdx.x; t < NB; t += 256) lh[t] = 0;
  __syncthreads();
  int e0 = blockIdx.x * 1024;
#pragma unroll
  for (int j = 0; j < 4; j++) {
    int e = e0 + j * 256 + threadIdx.x;
    if (e < E) atomicAdd(&lh[ei[E + e] >> BSH], 1);
  }
  __syncthreads();
  for (int t = threadIdx.x; t < NB; t += 256)
    gh[(size_t)blockIdx.x * NB + t] = lh[t];
}

// per-bucket exclusive scan over blocks: gh[b][c] -> prefix; btot[c] = total
__global__ __launch_bounds__(256) void scanA(int* __restrict__ gh, int* __restrict__ btot,
                                             int nblk, int NB) {
  int c = blockIdx.x;
  __shared__ int sc[256];
  int carry = 0;
  for (int b0 = 0; b0 < nblk; b0 += 256) {
    int b = b0 + threadIdx.x;
    int orig = (b < nblk) ? gh[(size_t)b * NB + c] : 0;
    int v = orig;
    sc[threadIdx.x] = v;
    __syncthreads();
    for (int off = 1; off < 256; off <<= 1) {
      int o = threadIdx.x >= off ? sc[threadIdx.x - off] : 0;
      __syncthreads();
      v += o;
      sc[threadIdx.x] = v;
      __syncthreads();
    }
    int ctot = sc[255];
    if (b < nblk) gh[(size_t)b * NB + c] = carry + v - orig;
    carry += ctot;
    __syncthreads();
  }
  if (threadIdx.x == 0) btot[c] = carry;
}

// exclusive scan of bucket totals -> bstart[0..NB], bstart[NB] = E
__global__ __launch_bounds__(256) void scanB(const int* __restrict__ btot,
                                             int* __restrict__ bstart, int NB) {
  __shared__ int sc[256];
  int base = threadIdx.x * 4;
  int c[4], s = 0;
#pragma unroll
  for (int j = 0; j < 4; j++) {
    int idx = base + j;
    c[j] = idx < NB ? btot[idx] : 0;
    s += c[j];
  }
  int v = s;
  sc[threadIdx.x] = v;
  __syncthreads();
  for (int off = 1; off < 256; off <<= 1) {
    int o = threadIdx.x >= off ? sc[threadIdx.x - off] : 0;
    __syncthreads();
    v += o;
    sc[threadIdx.x] = v;
    __syncthreads();
  }
  int run = v - s;
#pragma unroll
  for (int j = 0; j < 4; j++) {
    int idx = base + j;
    if (idx <= NB) bstart[idx] = run;
    run += c[j];
  }
}

// bin edges into bucket regions; block-local LDS ranking + precomputed bases
__global__ __launch_bounds__(256) void pass1(const int* __restrict__ ei,
                                             const float* __restrict__ w,
                                             const int* __restrict__ gh,
                                             const int* __restrict__ bstart,
                                             int4* __restrict__ pk1, int E, int NB) {
  __shared__ int lh[512];
  __shared__ int lbase[512];
  for (int t = threadIdx.x; t < NB; t += 256) lh[t] = 0;
  __syncthreads();
  int e0 = blockIdx.x * 1024;
  int s[4], d[4], r[4];
  float wv[4];
#pragma unroll
  for (int j = 0; j < 4; j++) {
    int e = e0 + j * 256 + threadIdx.x;
    if (e < E) {
      s[j] = ei[e];
      d[j] = ei[E + e];
      wv[j] = w[e];
      r[j] = atomicAdd(&lh[d[j] >> BSH], 1);
    }
  }
  __syncthreads();
  for (int t = threadIdx.x; t < NB; t += 256)
    lbase[t] = bstart[t] + gh[(size_t)blockIdx.x * NB + t];
  __syncthreads();
#pragma unroll
  for (int j = 0; j < 4; j++) {
    int e = e0 + j * 256 + threadIdx.x;
    if (e < E)
      pk1[lbase[d[j] >> BSH] + r[j]] = make_int4(s[j], d[j], __float_as_int(wv[j]), 0);
  }
}

// per-bucket exact counting sort (LDS) -> pk2 dst-sorted; emit dinv (deg in LDS)
__global__ __launch_bounds__(256) void pass2(const int4* __restrict__ pk1,
                                             const int* __restrict__ bstart,
                                             int4* __restrict__ pk2,
                                             float* __restrict__ dinv, int n) {
  int c = blockIdx.x;
  int dbase = c << BSH;
  __shared__ int h[BW];
  __shared__ float dg[BW];
  __shared__ int sc[BW];
  __shared__ int cur[BW];
  h[threadIdx.x] = 0;
  dg[threadIdx.x] = 0.f;
  __syncthreads();
  int e0 = bstart[c], e1 = bstart[c + 1];
  for (int e = e0 + threadIdx.x; e < e1; e += 256) {
    int4 p = pk1[e];
    int dl = p.y - dbase;
    atomicAdd(&h[dl], 1);
    atomicAdd(&dg[dl], __int_as_float(p.z));
  }
  __syncthreads();
  int own = h[threadIdx.x];
  int v = own;
  sc[threadIdx.x] = v;
  __syncthreads();
  for (int off = 1; off < 256; off <<= 1) {
    int o = threadIdx.x >= off ? sc[threadIdx.x - off] : 0;
    __syncthreads();
    v += o;
    sc[threadIdx.x] = v;
    __syncthreads();
  }
  cur[threadIdx.x] = e0 + v - own;           // exclusive start of this dst's run
  int i = dbase + threadIdx.x;
  if (i < n) dinv[i] = rsqrtf(dg[threadIdx.x] + 1.0f);   // self-loop +1
  __syncthreads();
  for (int e = e0 + threadIdx.x; e < e1; e += 256) {
    int4 p = pk1[e];
    int slot = atomicAdd(&cur[p.y - dbase], 1);
    pk2[slot] = p;                           // 64KB window: L2-local full lines
  }
}

// fold norm into pk2: .z = w * dinv[src] * dinv[dst]
__global__ void val_kernel(int4* __restrict__ pk, const float* __restrict__ dinv, int E) {
  int e = blockIdx.x * blockDim.x + threadIdx.x;
  if (e >= E) return;
  int4 p = pk[e];
  float v = __int_as_float(p.z) * dinv[p.x] * dinv[p.y];
  pk[e] = make_int4(p.x, p.y, __float_as_int(v), 0);
}

// ================= compute =================

// xl = A @ W (bf16 out) ; acc = xl*dinv^2 + bias (fp32, self-loop init fused)
__global__ __launch_bounds__(256) void gemm_init(const float* __restrict__ A,
                                                 const float* __restrict__ W,
                                                 const float* __restrict__ bias,
                                                 const float* __restrict__ dinv,
                                                 u16* __restrict__ xl,
                                                 float* __restrict__ acc, int n) {
  __shared__ float Wl[DF * DF];
  for (int t = threadIdx.x; t < DF * DF; t += 256) Wl[t] = W[t];
  __syncthreads();
  int f = threadIdx.x & 63;
  int sub = threadIdx.x >> 6;
  float bf = bias[f];
  for (int i = blockIdx.x * 4 + sub; i < n; i += gridDim.x * 4) {
    float xv = A[(size_t)i * DF + f];
    float r = 0.f;
#pragma unroll
    for (int k = 0; k < DF; k++) r += __shfl(xv, k, 64) * Wl[k * DF + f];
    xl[(size_t)i * DF + f] = f2bf(r);
    float di = dinv[i];
    acc[(size_t)i * DF + f] = r * di * di + bf;
  }
}

// xl2 = BN_PReLU(acc1) @ W (bf16 out) ; acc2 = xl2*dinv^2 + bias
__global__ __launch_bounds__(256) void gemm_bn_init(const float* __restrict__ accin,
                                                    const float* __restrict__ stats,
                                                    const float* __restrict__ alpha_p,
                                                    const float* __restrict__ W,
                                                    const float* __restrict__ bias,
                                                    const float* __restrict__ dinv,
                                                    u16* __restrict__ xl,
                                                    float* __restrict__ acc, int n) {
  __shared__ float Wl[DF * DF];
  for (int t = threadIdx.x; t < DF * DF; t += 256) Wl[t] = W[t];
  __syncthreads();
  int f = threadIdx.x & 63;
  int sub = threadIdx.x >> 6;
  float s = stats[128 + f], t0 = stats[192 + f], a = alpha_p[0], bf = bias[f];
  for (int i = blockIdx.x * 4 + sub; i < n; i += gridDim.x * 4) {
    float y = accin[(size_t)i * DF + f] * s + t0;
    y = (y >= 0.f) ? y : a * y;
    float r = 0.f;
#pragma unroll
    for (int k = 0; k < DF; k++) r += __shfl(y, k, 64) * Wl[k * DF + f];
    xl[(size_t)i * DF + f] = f2bf(r);
    float di = dinv[i];
    acc[(size_t)i * DF + f] = r * di * di + bf;
  }
}

// edge-parallel segmented reduction over dst-sorted pk2 (wave = 64 edges)
// bf16 xl gathers (128B/edge); norm preloaded in pk.z
__global__ __launch_bounds__(256) void edge_agg(const int4* __restrict__ pk,
                                                const u16* __restrict__ xl,
                                                float* __restrict__ acc, int E) {
  int w = blockIdx.x * 4 + (threadIdx.x >> 6);
  int lane = threadIdx.x & 63;
  long e0 = (long)w * 64;
  if (e0 >= E) return;
  long ei = e0 + lane;
  long idx = ei < E ? ei : (long)E - 1;
  int4 p = pk[idx];
  int c = p.x, d = p.y;
  float v = (ei < E) ? __int_as_float(p.z) : 0.f;
  float a = 0.f;
  int cur = __shfl(d, 0);
#pragma unroll
  for (int base = 0; base < 64; base += 16) {
    float xb[16];
#pragma unroll
    for (int j = 0; j < 16; j++) {
      int cj = __shfl(c, base + j);
      xb[j] = bf2f(xl[(size_t)cj * DF + lane]);   // 16 independent 128B gathers
    }
#pragma unroll
    for (int j = 0; j < 16; j++) {
      int dj = __shfl(d, base + j);
      float vj = __shfl(v, base + j);
      if (dj != cur) {                             // wave-uniform
        unsafeAtomicAdd(&acc[(size_t)cur * DF + lane], a);
        a = 0.f;
        cur = dj;
      }
      a = fmaf(vj, xb[j], a);
    }
  }
  unsafeAtomicAdd(&acc[(size_t)cur * DF + lane], a);
}

// per-feature sum / sumsq over nodes
__global__ void stats_kernel(const float* __restrict__ acc, float* __restrict__ stats, int n) {
  int f = threadIdx.x & 63;
  int sub = threadIdx.x >> 6;
  float s = 0.f, ss = 0.f;
  for (int i = blockIdx.x * 4 + sub; i < n; i += gridDim.x * 4) {
    float v = acc[(size_t)i * DF + f];
    s += v;
    ss += v * v;
  }
  __shared__ float ls[4][DF], lss[4][DF];
  ls[sub][f] = s;
  lss[sub][f] = ss;
  __syncthreads();
  if (threadIdx.x < DF) {
    float t1 = ls[0][f] + ls[1][f] + ls[2][f] + ls[3][f];
    float t2 = lss[0][f] + lss[1][f] + lss[2][f] + lss[3][f];
    unsafeAtomicAdd(&stats[f], t1);
    unsafeAtomicAdd(&stats[DF + f], t2);
  }
}

__global__ void finalize_stats(float* __restrict__ stats, const float* __restrict__ gamma,
                               const float* __restrict__ beta, int n) {
  int f = threadIdx.x;
  if (f >= DF) return;
  float mean = stats[f] / n;
  float var = stats[DF + f] / n - mean * mean;
  float rstd = rsqrtf(var + 1e-5f);
  float s = gamma[f] * rstd;
  stats[128 + f] = s;
  stats[192 + f] = beta[f] - mean * s;
}

__global__ void bnapply(const float* __restrict__ acc, const float* __restrict__ stats,
                        const float* __restrict__ alpha_p, float* __restrict__ outb, int n) {
  int i = blockIdx.x * 4 + (threadIdx.x >> 6);
  if (i >= n) return;
  int f = threadIdx.x & 63;
  float y = acc[(size_t)i * DF + f] * stats[128 + f] + stats[192 + f];
  float a = alpha_p[0];
  y = (y >= 0.f) ? y : a * y;
  outb[(size_t)i * DF + f] = y;
}

extern "C" void kernel_launch(void* const* d_in, const int* in_sizes, int n_in,
                              void* d_out, int out_size, void* d_ws, size_t ws_size,
                              hipStream_t stream) {
  const float* x  = (const float*)d_in[0];
  const int* ei   = (const int*)d_in[1];
  const float* w  = (const float*)d_in[2];
  const float* W1 = (const float*)d_in[3];
  const float* b1 = (const float*)d_in[4];
  const float* g1 = (const float*)d_in[5];
  const float* be1= (const float*)d_in[6];
  const float* al1= (const float*)d_in[7];
  const float* W2 = (const float*)d_in[8];
  const float* b2 = (const float*)d_in[9];
  const float* g2 = (const float*)d_in[10];
  const float* be2= (const float*)d_in[11];
  const float* al2= (const float*)d_in[12];
  float* out = (float*)d_out;

  const int n = in_sizes[0] / DF;
  const int E = in_sizes[2];
  const size_t na = ((size_t)n + 255) & ~(size_t)255;
  const int NB = (n + BW - 1) >> BSH;           // dst buckets (<=512)
  const int nblk1 = (E + 1023) / 1024;          // prehist/pass1 blocks
  const size_t ghsz = (((size_t)nblk1 * NB) + 3) & ~(size_t)3;

  // ---- workspace layout (4-byte units; pk arrays 16B-aligned) ----
  float* wsf = (float*)d_ws;
  float* stats1 = wsf;                          // 256
  float* stats2 = stats1 + 256;                 // 256
  int*   btot   = (int*)(stats2 + 256);         // 512
  int*   bstart = btot + 512;                   // 512 (NB+1 used)
  float* dinv   = (float*)(bstart + 512);       // na
  int*   gh     = (int*)(dinv + na);            // ghsz
  int4*  pk2    = (int4*)(gh + ghsz);           // E
  int*   U      = (int*)(pk2 + E);              // overlay: pk1 (4E) | XL16+ACC
  int4*  pk1    = (int4*)U;
  u16*   XL16   = (u16*)U;                      // na*64 bf16  (after pass2)
  float* ACC    = (float*)(U + na * 32);        // na*64 fp32

  const int nb_nodes = (n + 3) / 4;
  const int nb_e256  = (E + 255) / 256;
  const int nb_gemm  = 2048;
  const int nb_edge  = ((E + 63) / 64 + 3) / 4;
  const int nb_stats = 1024;

  hipMemsetAsync(stats1, 0, 512 * sizeof(float), stream);

  // ---- CSR build (bucket sort) ----
  prehist<<<nblk1, 256, 0, stream>>>(ei, gh, E, NB);
  scanA<<<NB, 256, 0, stream>>>(gh, btot, nblk1, NB);
  scanB<<<1, 256, 0, stream>>>(btot, bstart, NB);
  pass1<<<nblk1, 256, 0, stream>>>(ei, w, gh, bstart, pk1, E, NB);
  pass2<<<NB, 256, 0, stream>>>(pk1, bstart, pk2, dinv, n);
  val_kernel<<<nb_e256, 256, 0, stream>>>(pk2, dinv, E);

  // ---- layer 1 ----
  gemm_init<<<nb_gemm, 256, 0, stream>>>(x, W1, b1, dinv, XL16, ACC, n);
  edge_agg<<<nb_edge, 256, 0, stream>>>(pk2, XL16, ACC, E);
  stats_kernel<<<nb_stats, 256, 0, stream>>>(ACC, stats1, n);
  finalize_stats<<<1, 64, 0, stream>>>(stats1, g1, be1, n);

  // ---- layer 2 ----
  gemm_bn_init<<<nb_gemm, 256, 0, stream>>>(ACC, stats1, al1, W2, b2, dinv, XL16, ACC, n);
  edge_agg<<<nb_edge, 256, 0, stream>>>(pk2, XL16, ACC, E);
  stats_kernel<<<nb_stats, 256, 0, stream>>>(ACC, stats2, n);
  finalize_stats<<<1, 64, 0, stream>>>(stats2, g2, be2, n);
  bnapply<<<nb_nodes, 256, 0, stream>>>(ACC, stats2, al2, out, n);
}

// Round 7
// 408.392 us; speedup vs baseline: 4.2450x; 1.2713x over previous
//
#include <hip/hip_runtime.h>

#define DF 64
#define BSH 8              // bucket = dst >> 8  (256 dst per bucket)
#define BW  256

typedef unsigned short u16;
typedef unsigned int u32;
typedef __attribute__((ext_vector_type(8))) short short8;
typedef __attribute__((ext_vector_type(4))) float f32x4;

__device__ __forceinline__ float bf2f(u16 u) { return __uint_as_float(((u32)u) << 16); }
__device__ __forceinline__ u16 f2bf(float f) {
  u32 v = __float_as_uint(f);
  return (u16)((v + 0x7FFFu + ((v >> 16) & 1u)) >> 16);
}

// ============== bucket-sort CSR build (atomic-free globals) ==============

__global__ __launch_bounds__(256) void prehist(const int* __restrict__ ei,
                                               int* __restrict__ gh, int E, int NB) {
  __shared__ int lh[512];
  for (int t = threadIdx.x; t < NB; t += 256) lh[t] = 0;
  __syncthreads();
  int e0 = blockIdx.x * 1024;
#pragma unroll
  for (int j = 0; j < 4; j++) {
    int e = e0 + j * 256 + threadIdx.x;
    if (e < E) atomicAdd(&lh[ei[E + e] >> BSH], 1);
  }
  __syncthreads();
  for (int t = threadIdx.x; t < NB; t += 256)
    gh[(size_t)blockIdx.x * NB + t] = lh[t];
}

__global__ __launch_bounds__(256) void scanA(int* __restrict__ gh, int* __restrict__ btot,
                                             int nblk, int NB) {
  int c = blockIdx.x;
  __shared__ int sc[256];
  int carry = 0;
  for (int b0 = 0; b0 < nblk; b0 += 256) {
    int b = b0 + threadIdx.x;
    int orig = (b < nblk) ? gh[(size_t)b * NB + c] : 0;
    int v = orig;
    sc[threadIdx.x] = v;
    __syncthreads();
    for (int off = 1; off < 256; off <<= 1) {
      int o = threadIdx.x >= off ? sc[threadIdx.x - off] : 0;
      __syncthreads();
      v += o;
      sc[threadIdx.x] = v;
      __syncthreads();
    }
    int ctot = sc[255];
    if (b < nblk) gh[(size_t)b * NB + c] = carry + v - orig;
    carry += ctot;
    __syncthreads();
  }
  if (threadIdx.x == 0) btot[c] = carry;
}

__global__ __launch_bounds__(256) void scanB(const int* __restrict__ btot,
                                             int* __restrict__ bstart, int NB) {
  __shared__ int sc[256];
  int base = threadIdx.x * 4;
  int c[4], s = 0;
#pragma unroll
  for (int j = 0; j < 4; j++) {
    int idx = base + j;
    c[j] = idx < NB ? btot[idx] : 0;
    s += c[j];
  }
  int v = s;
  sc[threadIdx.x] = v;
  __syncthreads();
  for (int off = 1; off < 256; off <<= 1) {
    int o = threadIdx.x >= off ? sc[threadIdx.x - off] : 0;
    __syncthreads();
    v += o;
    sc[threadIdx.x] = v;
    __syncthreads();
  }
  int run = v - s;
#pragma unroll
  for (int j = 0; j < 4; j++) {
    int idx = base + j;
    if (idx <= NB) bstart[idx] = run;
    run += c[j];
  }
}

__global__ __launch_bounds__(256) void pass1(const int* __restrict__ ei,
                                             const float* __restrict__ w,
                                             const int* __restrict__ gh,
                                             const int* __restrict__ bstart,
                                             int4* __restrict__ pk1, int E, int NB) {
  __shared__ int lh[512];
  __shared__ int lbase[512];
  for (int t = threadIdx.x; t < NB; t += 256) lh[t] = 0;
  __syncthreads();
  int e0 = blockIdx.x * 1024;
  int s[4], d[4], r[4];
  float wv[4];
#pragma unroll
  for (int j = 0; j < 4; j++) {
    int e = e0 + j * 256 + threadIdx.x;
    if (e < E) {
      s[j] = ei[e];
      d[j] = ei[E + e];
      wv[j] = w[e];
      r[j] = atomicAdd(&lh[d[j] >> BSH], 1);
    }
  }
  __syncthreads();
  for (int t = threadIdx.x; t < NB; t += 256)
    lbase[t] = bstart[t] + gh[(size_t)blockIdx.x * NB + t];
  __syncthreads();
#pragma unroll
  for (int j = 0; j < 4; j++) {
    int e = e0 + j * 256 + threadIdx.x;
    if (e < E)
      pk1[lbase[d[j] >> BSH] + r[j]] = make_int4(s[j], d[j], __float_as_int(wv[j]), 0);
  }
}

__global__ __launch_bounds__(256) void pass2(const int4* __restrict__ pk1,
                                             const int* __restrict__ bstart,
                                             int4* __restrict__ pk2,
                                             float* __restrict__ dinv, int n) {
  int c = blockIdx.x;
  int dbase = c << BSH;
  __shared__ int h[BW];
  __shared__ float dg[BW];
  __shared__ int sc[BW];
  __shared__ int cur[BW];
  h[threadIdx.x] = 0;
  dg[threadIdx.x] = 0.f;
  __syncthreads();
  int e0 = bstart[c], e1 = bstart[c + 1];
  for (int e = e0 + threadIdx.x; e < e1; e += 256) {
    int4 p = pk1[e];
    int dl = p.y - dbase;
    atomicAdd(&h[dl], 1);
    atomicAdd(&dg[dl], __int_as_float(p.z));
  }
  __syncthreads();
  int own = h[threadIdx.x];
  int v = own;
  sc[threadIdx.x] = v;
  __syncthreads();
  for (int off = 1; off < 256; off <<= 1) {
    int o = threadIdx.x >= off ? sc[threadIdx.x - off] : 0;
    __syncthreads();
    v += o;
    sc[threadIdx.x] = v;
    __syncthreads();
  }
  cur[threadIdx.x] = e0 + v - own;
  int i = dbase + threadIdx.x;
  if (i < n) dinv[i] = rsqrtf(dg[threadIdx.x] + 1.0f);   // self-loop +1
  __syncthreads();
  for (int e = e0 + threadIdx.x; e < e1; e += 256) {
    int4 p = pk1[e];
    int slot = atomicAdd(&cur[p.y - dbase], 1);
    pk2[slot] = p;
  }
}

__global__ void val_kernel(int4* __restrict__ pk, const float* __restrict__ dinv, int E) {
  int e = blockIdx.x * blockDim.x + threadIdx.x;
  if (e >= E) return;
  int4 p = pk[e];
  float v = __int_as_float(p.z) * dinv[p.x] * dinv[p.y];
  pk[e] = make_int4(p.x, p.y, __float_as_int(v), 0);
}

// ================= compute =================

// B fragment for MFMA 16x16x32: B[k = k0+j][col], bf16-RNE from fp32 W
__device__ __forceinline__ short8 bfrag(const float* __restrict__ W, int k0, int col) {
  short8 b;
#pragma unroll
  for (int j = 0; j < 8; j++) b[j] = (short)f2bf(W[(k0 + j) * DF + col]);
  return b;
}

// MFMA GEMM: xl = bf16(A) @ bf16(W); acc = xl*dinv^2 + bias (self-loop init)
// wave = 16-row tile; B-frags in registers (loaded once); zero LDS/shfl.
__global__ __launch_bounds__(256) void gemm_init(const float* __restrict__ A,
                                                 const float* __restrict__ W,
                                                 const float* __restrict__ bias,
                                                 const float* __restrict__ dinv,
                                                 u16* __restrict__ xl,
                                                 float* __restrict__ accg, int n, int tiles) {
  int lane = threadIdx.x & 63;
  int m = lane & 15, quad = lane >> 4;
  int wid = blockIdx.x * 4 + (threadIdx.x >> 6);
  int nw = gridDim.x * 4;
  short8 B0[4], B1[4];
  float bb[4];
#pragma unroll
  for (int ft = 0; ft < 4; ft++) {
    B0[ft] = bfrag(W, quad * 8, ft * 16 + m);
    B1[ft] = bfrag(W, 32 + quad * 8, ft * 16 + m);
    bb[ft] = bias[ft * 16 + m];
  }
  for (int t = wid; t < tiles; t += nw) {
    int row0 = t * 16;
    int r = row0 + m;
    if (r >= n) r = n - 1;
    const float* ap = A + (size_t)r * DF + quad * 8;
    float4 u0 = *(const float4*)ap;
    float4 u1 = *(const float4*)(ap + 4);
    float4 u2 = *(const float4*)(ap + 32);
    float4 u3 = *(const float4*)(ap + 36);
    short8 a0, a1;
    a0[0]=(short)f2bf(u0.x); a0[1]=(short)f2bf(u0.y); a0[2]=(short)f2bf(u0.z); a0[3]=(short)f2bf(u0.w);
    a0[4]=(short)f2bf(u1.x); a0[5]=(short)f2bf(u1.y); a0[6]=(short)f2bf(u1.z); a0[7]=(short)f2bf(u1.w);
    a1[0]=(short)f2bf(u2.x); a1[1]=(short)f2bf(u2.y); a1[2]=(short)f2bf(u2.z); a1[3]=(short)f2bf(u2.w);
    a1[4]=(short)f2bf(u3.x); a1[5]=(short)f2bf(u3.y); a1[6]=(short)f2bf(u3.z); a1[7]=(short)f2bf(u3.w);
    f32x4 c[4];
#pragma unroll
    for (int ft = 0; ft < 4; ft++) c[ft] = (f32x4){0.f, 0.f, 0.f, 0.f};
#pragma unroll
    for (int ft = 0; ft < 4; ft++) {
      c[ft] = __builtin_amdgcn_mfma_f32_16x16x32_bf16(a0, B0[ft], c[ft], 0, 0, 0);
      c[ft] = __builtin_amdgcn_mfma_f32_16x16x32_bf16(a1, B1[ft], c[ft], 0, 0, 0);
    }
    float dd[4];
#pragma unroll
    for (int reg = 0; reg < 4; reg++) {
      int r2 = row0 + quad * 4 + reg;
      dd[reg] = (r2 < n) ? dinv[r2] : 0.f;
    }
#pragma unroll
    for (int ft = 0; ft < 4; ft++)
#pragma unroll
      for (int reg = 0; reg < 4; reg++) {
        int r2 = row0 + quad * 4 + reg;
        if (r2 < n) {
          float v = c[ft][reg];
          xl[(size_t)r2 * DF + ft * 16 + m] = f2bf(v);
          accg[(size_t)r2 * DF + ft * 16 + m] = v * dd[reg] * dd[reg] + bb[ft];
        }
      }
  }
}

// MFMA GEMM with BN+PReLU fused into A-load: xl2 = bf16(BN_PReLU(acc1)) @ W2
__global__ __launch_bounds__(256) void gemm_bn_init(const float* __restrict__ accin,
                                                    const float* __restrict__ stats,
                                                    const float* __restrict__ alpha_p,
                                                    const float* __restrict__ W,
                                                    const float* __restrict__ bias,
                                                    const float* __restrict__ dinv,
                                                    u16* __restrict__ xl,
                                                    float* __restrict__ accg, int n, int tiles) {
  int lane = threadIdx.x & 63;
  int m = lane & 15, quad = lane >> 4;
  int wid = blockIdx.x * 4 + (threadIdx.x >> 6);
  int nw = gridDim.x * 4;
  short8 B0[4], B1[4];
  float bb[4];
#pragma unroll
  for (int ft = 0; ft < 4; ft++) {
    B0[ft] = bfrag(W, quad * 8, ft * 16 + m);
    B1[ft] = bfrag(W, 32 + quad * 8, ft * 16 + m);
    bb[ft] = bias[ft * 16 + m];
  }
  float s0[8], t0[8], s1[8], t1[8];
#pragma unroll
  for (int j = 0; j < 8; j++) {
    s0[j] = stats[128 + quad * 8 + j];
    t0[j] = stats[192 + quad * 8 + j];
    s1[j] = stats[128 + 32 + quad * 8 + j];
    t1[j] = stats[192 + 32 + quad * 8 + j];
  }
  float al = alpha_p[0];
  for (int t = wid; t < tiles; t += nw) {
    int row0 = t * 16;
    int r = row0 + m;
    if (r >= n) r = n - 1;
    const float* ap = accin + (size_t)r * DF + quad * 8;
    float h0[8], h1[8];
#pragma unroll
    for (int j = 0; j < 8; j++) { h0[j] = ap[j]; h1[j] = ap[32 + j]; }
    short8 a0, a1;
#pragma unroll
    for (int j = 0; j < 8; j++) {
      float y0 = h0[j] * s0[j] + t0[j];
      y0 = (y0 >= 0.f) ? y0 : al * y0;
      a0[j] = (short)f2bf(y0);
      float y1 = h1[j] * s1[j] + t1[j];
      y1 = (y1 >= 0.f) ? y1 : al * y1;
      a1[j] = (short)f2bf(y1);
    }
    f32x4 c[4];
#pragma unroll
    for (int ft = 0; ft < 4; ft++) c[ft] = (f32x4){0.f, 0.f, 0.f, 0.f};
#pragma unroll
    for (int ft = 0; ft < 4; ft++) {
      c[ft] = __builtin_amdgcn_mfma_f32_16x16x32_bf16(a0, B0[ft], c[ft], 0, 0, 0);
      c[ft] = __builtin_amdgcn_mfma_f32_16x16x32_bf16(a1, B1[ft], c[ft], 0, 0, 0);
    }
    float dd[4];
#pragma unroll
    for (int reg = 0; reg < 4; reg++) {
      int r2 = row0 + quad * 4 + reg;
      dd[reg] = (r2 < n) ? dinv[r2] : 0.f;
    }
#pragma unroll
    for (int ft = 0; ft < 4; ft++)
#pragma unroll
      for (int reg = 0; reg < 4; reg++) {
        int r2 = row0 + quad * 4 + reg;
        if (r2 < n) {
          float v = c[ft][reg];
          xl[(size_t)r2 * DF + ft * 16 + m] = f2bf(v);
          accg[(size_t)r2 * DF + ft * 16 + m] = v * dd[reg] * dd[reg] + bb[ft];
        }
      }
  }
}

// edge-parallel segmented reduction over dst-sorted pk2 (wave = 64 edges)
__global__ __launch_bounds__(256) void edge_agg(const int4* __restrict__ pk,
                                                const u16* __restrict__ xl,
                                                float* __restrict__ acc, int E) {
  int w = blockIdx.x * 4 + (threadIdx.x >> 6);
  int lane = threadIdx.x & 63;
  long e0 = (long)w * 64;
  if (e0 >= E) return;
  long ei = e0 + lane;
  long idx = ei < E ? ei : (long)E - 1;
  int4 p = pk[idx];
  int c = p.x, d = p.y;
  float v = (ei < E) ? __int_as_float(p.z) : 0.f;
  float a = 0.f;
  int cur = __shfl(d, 0);
#pragma unroll
  for (int base = 0; base < 64; base += 16) {
    float xb[16];
#pragma unroll
    for (int j = 0; j < 16; j++) {
      int cj = __shfl(c, base + j);
      xb[j] = bf2f(xl[(size_t)cj * DF + lane]);
    }
#pragma unroll
    for (int j = 0; j < 16; j++) {
      int dj = __shfl(d, base + j);
      float vj = __shfl(v, base + j);
      if (dj != cur) {
        unsafeAtomicAdd(&acc[(size_t)cur * DF + lane], a);
        a = 0.f;
        cur = dj;
      }
      a = fmaf(vj, xb[j], a);
    }
  }
  unsafeAtomicAdd(&acc[(size_t)cur * DF + lane], a);
}

__global__ void stats_kernel(const float* __restrict__ acc, float* __restrict__ stats, int n) {
  int f = threadIdx.x & 63;
  int sub = threadIdx.x >> 6;
  float s = 0.f, ss = 0.f;
  for (int i = blockIdx.x * 4 + sub; i < n; i += gridDim.x * 4) {
    float v = acc[(size_t)i * DF + f];
    s += v;
    ss += v * v;
  }
  __shared__ float ls[4][DF], lss[4][DF];
  ls[sub][f] = s;
  lss[sub][f] = ss;
  __syncthreads();
  if (threadIdx.x < DF) {
    float t1 = ls[0][f] + ls[1][f] + ls[2][f] + ls[3][f];
    float t2 = lss[0][f] + lss[1][f] + lss[2][f] + lss[3][f];
    unsafeAtomicAdd(&stats[f], t1);
    unsafeAtomicAdd(&stats[DF + f], t2);
  }
}

__global__ void finalize_stats(float* __restrict__ stats, const float* __restrict__ gamma,
                               const float* __restrict__ beta, int n) {
  int f = threadIdx.x;
  if (f >= DF) return;
  float mean = stats[f] / n;
  float var = stats[DF + f] / n - mean * mean;
  float rstd = rsqrtf(var + 1e-5f);
  float s = gamma[f] * rstd;
  stats[128 + f] = s;
  stats[192 + f] = beta[f] - mean * s;
}

__global__ void bnapply(const float* __restrict__ acc, const float* __restrict__ stats,
                        const float* __restrict__ alpha_p, float* __restrict__ outb, int n) {
  int i = blockIdx.x * 4 + (threadIdx.x >> 6);
  if (i >= n) return;
  int f = threadIdx.x & 63;
  float y = acc[(size_t)i * DF + f] * stats[128 + f] + stats[192 + f];
  float a = alpha_p[0];
  y = (y >= 0.f) ? y : a * y;
  outb[(size_t)i * DF + f] = y;
}

extern "C" void kernel_launch(void* const* d_in, const int* in_sizes, int n_in,
                              void* d_out, int out_size, void* d_ws, size_t ws_size,
                              hipStream_t stream) {
  const float* x  = (const float*)d_in[0];
  const int* ei   = (const int*)d_in[1];
  const float* w  = (const float*)d_in[2];
  const float* W1 = (const float*)d_in[3];
  const float* b1 = (const float*)d_in[4];
  const float* g1 = (const float*)d_in[5];
  const float* be1= (const float*)d_in[6];
  const float* al1= (const float*)d_in[7];
  const float* W2 = (const float*)d_in[8];
  const float* b2 = (const float*)d_in[9];
  const float* g2 = (const float*)d_in[10];
  const float* be2= (const float*)d_in[11];
  const float* al2= (const float*)d_in[12];
  float* out = (float*)d_out;

  const int n = in_sizes[0] / DF;
  const int E = in_sizes[2];
  const size_t na = ((size_t)n + 255) & ~(size_t)255;
  const int NB = (n + BW - 1) >> BSH;
  const int nblk1 = (E + 1023) / 1024;
  const size_t ghsz = (((size_t)nblk1 * NB) + 3) & ~(size_t)3;
  const int tiles = (n + 15) / 16;

  // ---- workspace layout ----
  float* wsf = (float*)d_ws;
  float* stats1 = wsf;                          // 256
  float* stats2 = stats1 + 256;                 // 256
  int*   btot   = (int*)(stats2 + 256);         // 512
  int*   bstart = btot + 512;                   // 512 (NB+1 used)
  float* dinv   = (float*)(bstart + 512);       // na
  int*   gh     = (int*)(dinv + na);            // ghsz
  int4*  pk2    = (int4*)(gh + ghsz);           // E
  int*   U      = (int*)(pk2 + E);              // overlay: pk1 (4E) | XL16+ACC
  int4*  pk1    = (int4*)U;
  u16*   XL16   = (u16*)U;                      // na*64 bf16 (after pass2)
  float* ACC    = (float*)(U + na * 32);        // na*64 fp32

  const int nb_nodes = (n + 3) / 4;
  const int nb_e256  = (E + 255) / 256;
  const int nb_gemm  = 512;                     // grid-stride over 16-row tiles
  const int nb_edge  = ((E + 63) / 64 + 3) / 4;
  const int nb_stats = 1024;

  hipMemsetAsync(stats1, 0, 512 * sizeof(float), stream);

  // ---- CSR build (bucket sort) ----
  prehist<<<nblk1, 256, 0, stream>>>(ei, gh, E, NB);
  scanA<<<NB, 256, 0, stream>>>(gh, btot, nblk1, NB);
  scanB<<<1, 256, 0, stream>>>(btot, bstart, NB);
  pass1<<<nblk1, 256, 0, stream>>>(ei, w, gh, bstart, pk1, E, NB);
  pass2<<<NB, 256, 0, stream>>>(pk1, bstart, pk2, dinv, n);
  val_kernel<<<nb_e256, 256, 0, stream>>>(pk2, dinv, E);

  // ---- layer 1 ----
  gemm_init<<<nb_gemm, 256, 0, stream>>>(x, W1, b1, dinv, XL16, ACC, n, tiles);
  edge_agg<<<nb_edge, 256, 0, stream>>>(pk2, XL16, ACC, E);
  stats_kernel<<<nb_stats, 256, 0, stream>>>(ACC, stats1, n);
  finalize_stats<<<1, 64, 0, stream>>>(stats1, g1, be1, n);

  // ---- layer 2 ----
  gemm_bn_init<<<nb_gemm, 256, 0, stream>>>(ACC, stats1, al1, W2, b2, dinv, XL16, ACC, n, tiles);
  edge_agg<<<nb_edge, 256, 0, stream>>>(pk2, XL16, ACC, E);
  stats_kernel<<<nb_stats, 256, 0, stream>>>(ACC, stats2, n);
  finalize_stats<<<1, 64, 0, stream>>>(stats2, g2, be2, n);
  bnapply<<<nb_nodes, 256, 0, stream>>>(ACC, stats2, al2, out, n);
}

// Round 8
// 360.457 us; speedup vs baseline: 4.8095x; 1.1330x over previous
//
#include <hip/hip_runtime.h>

#define DF 64
#define BSH 8              // bucket = dst >> 8  (256 dst per bucket)
#define BW  256

typedef unsigned short u16;
typedef unsigned int u32;
typedef __attribute__((ext_vector_type(8))) short short8;
typedef __attribute__((ext_vector_type(4))) float f32x4;

__device__ __forceinline__ float bf2f(u16 u) { return __uint_as_float(((u32)u) << 16); }
__device__ __forceinline__ u16 f2bf(float f) {
  u32 v = __float_as_uint(f);
  return (u16)((v + 0x7FFFu + ((v >> 16) & 1u)) >> 16);
}

// ============== bucket-sort CSR build (atomic-free globals) ==============

__global__ __launch_bounds__(256) void prehist(const int* __restrict__ ei,
                                               int* __restrict__ gh, int E, int NB) {
  __shared__ int lh[512];
  for (int t = threadIdx.x; t < NB; t += 256) lh[t] = 0;
  __syncthreads();
  int e0 = blockIdx.x * 1024;
#pragma unroll
  for (int j = 0; j < 4; j++) {
    int e = e0 + j * 256 + threadIdx.x;
    if (e < E) atomicAdd(&lh[ei[E + e] >> BSH], 1);
  }
  __syncthreads();
  for (int t = threadIdx.x; t < NB; t += 256)
    gh[(size_t)blockIdx.x * NB + t] = lh[t];
}

__global__ __launch_bounds__(256) void scanA(int* __restrict__ gh, int* __restrict__ btot,
                                             int nblk, int NB) {
  int c = blockIdx.x;
  __shared__ int sc[256];
  int carry = 0;
  for (int b0 = 0; b0 < nblk; b0 += 256) {
    int b = b0 + threadIdx.x;
    int orig = (b < nblk) ? gh[(size_t)b * NB + c] : 0;
    int v = orig;
    sc[threadIdx.x] = v;
    __syncthreads();
    for (int off = 1; off < 256; off <<= 1) {
      int o = threadIdx.x >= off ? sc[threadIdx.x - off] : 0;
      __syncthreads();
      v += o;
      sc[threadIdx.x] = v;
      __syncthreads();
    }
    int ctot = sc[255];
    if (b < nblk) gh[(size_t)b * NB + c] = carry + v - orig;
    carry += ctot;
    __syncthreads();
  }
  if (threadIdx.x == 0) btot[c] = carry;
}

__global__ __launch_bounds__(256) void scanB(const int* __restrict__ btot,
                                             int* __restrict__ bstart, int NB) {
  __shared__ int sc[256];
  int base = threadIdx.x * 4;
  int c[4], s = 0;
#pragma unroll
  for (int j = 0; j < 4; j++) {
    int idx = base + j;
    c[j] = idx < NB ? btot[idx] : 0;
    s += c[j];
  }
  int v = s;
  sc[threadIdx.x] = v;
  __syncthreads();
  for (int off = 1; off < 256; off <<= 1) {
    int o = threadIdx.x >= off ? sc[threadIdx.x - off] : 0;
    __syncthreads();
    v += o;
    sc[threadIdx.x] = v;
    __syncthreads();
  }
  int run = v - s;
#pragma unroll
  for (int j = 0; j < 4; j++) {
    int idx = base + j;
    if (idx <= NB) bstart[idx] = run;
    run += c[j];
  }
}

// bin edges into dst-buckets; 8B records {dl | src<<8, w_fp32}
__global__ __launch_bounds__(256) void pass1(const int* __restrict__ ei,
                                             const float* __restrict__ w,
                                             const int* __restrict__ gh,
                                             const int* __restrict__ bstart,
                                             int2* __restrict__ pk1, int E, int NB) {
  __shared__ int lh[512];
  __shared__ int lbase[512];
  for (int t = threadIdx.x; t < NB; t += 256) lh[t] = 0;
  __syncthreads();
  int e0 = blockIdx.x * 1024;
  int s[4], d[4], r[4];
  float wv[4];
#pragma unroll
  for (int j = 0; j < 4; j++) {
    int e = e0 + j * 256 + threadIdx.x;
    if (e < E) {
      s[j] = ei[e];
      d[j] = ei[E + e];
      wv[j] = w[e];
      r[j] = atomicAdd(&lh[d[j] >> BSH], 1);
    }
  }
  __syncthreads();
  for (int t = threadIdx.x; t < NB; t += 256)
    lbase[t] = bstart[t] + gh[(size_t)blockIdx.x * NB + t];
  __syncthreads();
#pragma unroll
  for (int j = 0; j < 4; j++) {
    int e = e0 + j * 256 + threadIdx.x;
    if (e < E)
      pk1[lbase[d[j] >> BSH] + r[j]] =
          make_int2((d[j] & 255) | (s[j] << 8), __float_as_int(wv[j]));
  }
}

// per-bucket counting sort (LDS) -> pk2 {src | dl<<17, w_fp32}; emit dinv
__global__ __launch_bounds__(256) void pass2(const int2* __restrict__ pk1,
                                             const int* __restrict__ bstart,
                                             int2* __restrict__ pk2,
                                             float* __restrict__ dinv, int n) {
  int c = blockIdx.x;
  int dbase = c << BSH;
  __shared__ int h[BW];
  __shared__ float dg[BW];
  __shared__ int sc[BW];
  __shared__ int cur[BW];
  h[threadIdx.x] = 0;
  dg[threadIdx.x] = 0.f;
  __syncthreads();
  int e0 = bstart[c], e1 = bstart[c + 1];
  for (int e = e0 + threadIdx.x; e < e1; e += 256) {
    int2 p = pk1[e];
    int dl = p.x & 255;
    atomicAdd(&h[dl], 1);
    atomicAdd(&dg[dl], __int_as_float(p.y));
  }
  __syncthreads();
  int own = h[threadIdx.x];
  int v = own;
  sc[threadIdx.x] = v;
  __syncthreads();
  for (int off = 1; off < 256; off <<= 1) {
    int o = threadIdx.x >= off ? sc[threadIdx.x - off] : 0;
    __syncthreads();
    v += o;
    sc[threadIdx.x] = v;
    __syncthreads();
  }
  cur[threadIdx.x] = e0 + v - own;
  int i = dbase + threadIdx.x;
  if (i < n) dinv[i] = rsqrtf(dg[threadIdx.x] + 1.0f);   // self-loop +1
  __syncthreads();
  for (int e = e0 + threadIdx.x; e < e1; e += 256) {
    int2 p = pk1[e];
    int dl = p.x & 255;
    int slot = atomicAdd(&cur[dl], 1);
    pk2[slot] = make_int2((p.x >> 8) | (dl << 17), p.y);
  }
}

// finalize records: w1 = db | bf16(w*dinv[s]*dinv[d])<<16 ; one block per bucket
__global__ __launch_bounds__(256) void val_kernel(int2* __restrict__ pk,
                                                  const int* __restrict__ bstart,
                                                  const float* __restrict__ dinv,
                                                  int E, int NB) {
  int db = blockIdx.x;
  int e0 = bstart[db], e1 = bstart[db + 1];
  for (int e = e0 + threadIdx.x; e < e1; e += 256) {
    int2 p = pk[e];
    int s = p.x & 0x1FFFF;
    int d = (db << BSH) | ((p.x >> 17) & 255);
    float v = __int_as_float(p.y) * dinv[s] * dinv[d];
    pk[e] = make_int2(p.x, db | ((int)f2bf(v) << 16));
  }
  if (db == 0 && threadIdx.x < 64)                       // pad to wave multiple
    pk[E + threadIdx.x] = make_int2(0, 0);               // dst=0, val=0
}

// ================= compute =================

// B fragment for MFMA 16x16x32: B[k = k0+j][col], bf16-RNE from fp32 W
__device__ __forceinline__ short8 bfrag(const float* __restrict__ W, int k0, int col) {
  short8 b;
#pragma unroll
  for (int j = 0; j < 8; j++) b[j] = (short)f2bf(W[(k0 + j) * DF + col]);
  return b;
}

// MFMA GEMM: xl = bf16(A) @ bf16(W); acc = xl*dinv^2 + bias (self-loop init)
__global__ __launch_bounds__(256) void gemm_init(const float* __restrict__ A,
                                                 const float* __restrict__ W,
                                                 const float* __restrict__ bias,
                                                 const float* __restrict__ dinv,
                                                 u16* __restrict__ xl,
                                                 float* __restrict__ accg, int n, int tiles) {
  int lane = threadIdx.x & 63;
  int m = lane & 15, quad = lane >> 4;
  int wid = blockIdx.x * 4 + (threadIdx.x >> 6);
  int nw = gridDim.x * 4;
  short8 B0[4], B1[4];
  float bb[4];
#pragma unroll
  for (int ft = 0; ft < 4; ft++) {
    B0[ft] = bfrag(W, quad * 8, ft * 16 + m);
    B1[ft] = bfrag(W, 32 + quad * 8, ft * 16 + m);
    bb[ft] = bias[ft * 16 + m];
  }
  for (int t = wid; t < tiles; t += nw) {
    int row0 = t * 16;
    int r = row0 + m;
    if (r >= n) r = n - 1;
    const float* ap = A + (size_t)r * DF + quad * 8;
    float4 u0 = *(const float4*)ap;
    float4 u1 = *(const float4*)(ap + 4);
    float4 u2 = *(const float4*)(ap + 32);
    float4 u3 = *(const float4*)(ap + 36);
    short8 a0, a1;
    a0[0]=(short)f2bf(u0.x); a0[1]=(short)f2bf(u0.y); a0[2]=(short)f2bf(u0.z); a0[3]=(short)f2bf(u0.w);
    a0[4]=(short)f2bf(u1.x); a0[5]=(short)f2bf(u1.y); a0[6]=(short)f2bf(u1.z); a0[7]=(short)f2bf(u1.w);
    a1[0]=(short)f2bf(u2.x); a1[1]=(short)f2bf(u2.y); a1[2]=(short)f2bf(u2.z); a1[3]=(short)f2bf(u2.w);
    a1[4]=(short)f2bf(u3.x); a1[5]=(short)f2bf(u3.y); a1[6]=(short)f2bf(u3.z); a1[7]=(short)f2bf(u3.w);
    f32x4 c[4];
#pragma unroll
    for (int ft = 0; ft < 4; ft++) c[ft] = (f32x4){0.f, 0.f, 0.f, 0.f};
#pragma unroll
    for (int ft = 0; ft < 4; ft++) {
      c[ft] = __builtin_amdgcn_mfma_f32_16x16x32_bf16(a0, B0[ft], c[ft], 0, 0, 0);
      c[ft] = __builtin_amdgcn_mfma_f32_16x16x32_bf16(a1, B1[ft], c[ft], 0, 0, 0);
    }
    float dd[4];
#pragma unroll
    for (int reg = 0; reg < 4; reg++) {
      int r2 = row0 + quad * 4 + reg;
      dd[reg] = (r2 < n) ? dinv[r2] : 0.f;
    }
#pragma unroll
    for (int ft = 0; ft < 4; ft++)
#pragma unroll
      for (int reg = 0; reg < 4; reg++) {
        int r2 = row0 + quad * 4 + reg;
        if (r2 < n) {
          float v = c[ft][reg];
          xl[(size_t)r2 * DF + ft * 16 + m] = f2bf(v);
          accg[(size_t)r2 * DF + ft * 16 + m] = v * dd[reg] * dd[reg] + bb[ft];
        }
      }
  }
}

// MFMA GEMM with BN+PReLU fused into A-load
__global__ __launch_bounds__(256) void gemm_bn_init(const float* __restrict__ accin,
                                                    const float* __restrict__ stats,
                                                    const float* __restrict__ alpha_p,
                                                    const float* __restrict__ W,
                                                    const float* __restrict__ bias,
                                                    const float* __restrict__ dinv,
                                                    u16* __restrict__ xl,
                                                    float* __restrict__ accg, int n, int tiles) {
  int lane = threadIdx.x & 63;
  int m = lane & 15, quad = lane >> 4;
  int wid = blockIdx.x * 4 + (threadIdx.x >> 6);
  int nw = gridDim.x * 4;
  short8 B0[4], B1[4];
  float bb[4];
#pragma unroll
  for (int ft = 0; ft < 4; ft++) {
    B0[ft] = bfrag(W, quad * 8, ft * 16 + m);
    B1[ft] = bfrag(W, 32 + quad * 8, ft * 16 + m);
    bb[ft] = bias[ft * 16 + m];
  }
  float s0[8], t0[8], s1[8], t1[8];
#pragma unroll
  for (int j = 0; j < 8; j++) {
    s0[j] = stats[128 + quad * 8 + j];
    t0[j] = stats[192 + quad * 8 + j];
    s1[j] = stats[128 + 32 + quad * 8 + j];
    t1[j] = stats[192 + 32 + quad * 8 + j];
  }
  float al = alpha_p[0];
  for (int t = wid; t < tiles; t += nw) {
    int row0 = t * 16;
    int r = row0 + m;
    if (r >= n) r = n - 1;
    const float* ap = accin + (size_t)r * DF + quad * 8;
    float h0[8], h1[8];
#pragma unroll
    for (int j = 0; j < 8; j++) { h0[j] = ap[j]; h1[j] = ap[32 + j]; }
    short8 a0, a1;
#pragma unroll
    for (int j = 0; j < 8; j++) {
      float y0 = h0[j] * s0[j] + t0[j];
      y0 = (y0 >= 0.f) ? y0 : al * y0;
      a0[j] = (short)f2bf(y0);
      float y1 = h1[j] * s1[j] + t1[j];
      y1 = (y1 >= 0.f) ? y1 : al * y1;
      a1[j] = (short)f2bf(y1);
    }
    f32x4 c[4];
#pragma unroll
    for (int ft = 0; ft < 4; ft++) c[ft] = (f32x4){0.f, 0.f, 0.f, 0.f};
#pragma unroll
    for (int ft = 0; ft < 4; ft++) {
      c[ft] = __builtin_amdgcn_mfma_f32_16x16x32_bf16(a0, B0[ft], c[ft], 0, 0, 0);
      c[ft] = __builtin_amdgcn_mfma_f32_16x16x32_bf16(a1, B1[ft], c[ft], 0, 0, 0);
    }
    float dd[4];
#pragma unroll
    for (int reg = 0; reg < 4; reg++) {
      int r2 = row0 + quad * 4 + reg;
      dd[reg] = (r2 < n) ? dinv[r2] : 0.f;
    }
#pragma unroll
    for (int ft = 0; ft < 4; ft++)
#pragma unroll
      for (int reg = 0; reg < 4; reg++) {
        int r2 = row0 + quad * 4 + reg;
        if (r2 < n) {
          float v = c[ft][reg];
          xl[(size_t)r2 * DF + ft * 16 + m] = f2bf(v);
          accg[(size_t)r2 * DF + ft * 16 + m] = v * dd[reg] * dd[reg] + bb[ft];
        }
      }
  }
}

// edge-parallel segmented reduction; wave = 64 dst-sorted edges.
// pk reads are wave-uniform (scalar s_load path) — zero shuffles.
__global__ __launch_bounds__(256) void edge_agg(const int2* __restrict__ pk,
                                                const u16* __restrict__ xl,
                                                float* __restrict__ acc, int E) {
  int wv = blockIdx.x * 4 + (threadIdx.x >> 6);
  int lane = threadIdx.x & 63;
  int wu = __builtin_amdgcn_readfirstlane(wv);
  if (wu * 64 >= E) return;
  const int2* __restrict__ pw = pk + ((size_t)wu << 6);
  int2 p0 = pw[0];
  int cur = ((p0.y & 511) << BSH) | ((p0.x >> 17) & 255);
  float a = 0.f;
#pragma unroll
  for (int base = 0; base < 64; base += 16) {
    int sj[16], dj[16];
    float vj[16];
#pragma unroll
    for (int j = 0; j < 16; j++) {
      int2 p = pw[base + j];
      sj[j] = p.x & 0x1FFFF;
      dj[j] = ((p.y & 511) << BSH) | ((p.x >> 17) & 255);
      vj[j] = bf2f((u16)((u32)p.y >> 16));
    }
    float xb[16];
#pragma unroll
    for (int j = 0; j < 16; j++)
      xb[j] = bf2f(xl[((size_t)sj[j] << 6) | lane]);   // 16 independent 128B gathers
#pragma unroll
    for (int j = 0; j < 16; j++) {
      if (dj[j] != cur) {                               // wave-uniform branch
        unsafeAtomicAdd(&acc[((size_t)cur << 6) | lane], a);
        a = 0.f;
        cur = dj[j];
      }
      a = fmaf(vj[j], xb[j], a);
    }
  }
  unsafeAtomicAdd(&acc[((size_t)cur << 6) | lane], a);
}

__global__ void stats_kernel(const float* __restrict__ acc, float* __restrict__ stats, int n) {
  int f = threadIdx.x & 63;
  int sub = threadIdx.x >> 6;
  float s = 0.f, ss = 0.f;
  for (int i = blockIdx.x * 4 + sub; i < n; i += gridDim.x * 4) {
    float v = acc[(size_t)i * DF + f];
    s += v;
    ss += v * v;
  }
  __shared__ float ls[4][DF], lss[4][DF];
  ls[sub][f] = s;
  lss[sub][f] = ss;
  __syncthreads();
  if (threadIdx.x < DF) {
    float t1 = ls[0][f] + ls[1][f] + ls[2][f] + ls[3][f];
    float t2 = lss[0][f] + lss[1][f] + lss[2][f] + lss[3][f];
    unsafeAtomicAdd(&stats[f], t1);
    unsafeAtomicAdd(&stats[DF + f], t2);
  }
}

__global__ void finalize_stats(float* __restrict__ stats, const float* __restrict__ gamma,
                               const float* __restrict__ beta, int n) {
  int f = threadIdx.x;
  if (f >= DF) return;
  float mean = stats[f] / n;
  float var = stats[DF + f] / n - mean * mean;
  float rstd = rsqrtf(var + 1e-5f);
  float s = gamma[f] * rstd;
  stats[128 + f] = s;
  stats[192 + f] = beta[f] - mean * s;
}

__global__ void bnapply(const float* __restrict__ acc, const float* __restrict__ stats,
                        const float* __restrict__ alpha_p, float* __restrict__ outb, int n) {
  int i = blockIdx.x * 4 + (threadIdx.x >> 6);
  if (i >= n) return;
  int f = threadIdx.x & 63;
  float y = acc[(size_t)i * DF + f] * stats[128 + f] + stats[192 + f];
  float a = alpha_p[0];
  y = (y >= 0.f) ? y : a * y;
  outb[(size_t)i * DF + f] = y;
}

extern "C" void kernel_launch(void* const* d_in, const int* in_sizes, int n_in,
                              void* d_out, int out_size, void* d_ws, size_t ws_size,
                              hipStream_t stream) {
  const float* x  = (const float*)d_in[0];
  const int* ei   = (const int*)d_in[1];
  const float* w  = (const float*)d_in[2];
  const float* W1 = (const float*)d_in[3];
  const float* b1 = (const float*)d_in[4];
  const float* g1 = (const float*)d_in[5];
  const float* be1= (const float*)d_in[6];
  const float* al1= (const float*)d_in[7];
  const float* W2 = (const float*)d_in[8];
  const float* b2 = (const float*)d_in[9];
  const float* g2 = (const float*)d_in[10];
  const float* be2= (const float*)d_in[11];
  const float* al2= (const float*)d_in[12];
  float* out = (float*)d_out;

  const int n = in_sizes[0] / DF;
  const int E = in_sizes[2];
  const size_t na = ((size_t)n + 255) & ~(size_t)255;
  const int NB = (n + BW - 1) >> BSH;
  const int nblk1 = (E + 1023) / 1024;
  const size_t ghsz = (((size_t)nblk1 * NB) + 3) & ~(size_t)3;
  const int tiles = (n + 15) / 16;

  // ---- workspace layout (4-byte units; int2 arrays 8B-aligned) ----
  float* wsf = (float*)d_ws;
  float* stats1 = wsf;                          // 256
  float* stats2 = stats1 + 256;                 // 256
  int*   btot   = (int*)(stats2 + 256);         // 512
  int*   bstart = btot + 512;                   // 512 (NB+1 used)
  float* dinv   = (float*)(bstart + 512);       // na
  int*   gh     = (int*)(dinv + na);            // ghsz
  int2*  pk2    = (int2*)(gh + ghsz);           // E+64 records (8B each)
  int*   U      = (int*)(pk2 + (E + 64));       // overlay: pk1 (2E) | XL16+ACC
  int2*  pk1    = (int2*)U;
  u16*   XL16   = (u16*)U;                      // na*64 bf16 (after pass2)
  float* ACC    = (float*)(U + na * 32);        // na*64 fp32

  const int nb_nodes = (n + 3) / 4;
  const int nb_gemm  = 512;
  const int nb_edge  = ((E + 63) / 64 + 3) / 4;
  const int nb_stats = 1024;

  hipMemsetAsync(stats1, 0, 512 * sizeof(float), stream);

  // ---- CSR build (bucket sort, 8B records) ----
  prehist<<<nblk1, 256, 0, stream>>>(ei, gh, E, NB);
  scanA<<<NB, 256, 0, stream>>>(gh, btot, nblk1, NB);
  scanB<<<1, 256, 0, stream>>>(btot, bstart, NB);
  pass1<<<nblk1, 256, 0, stream>>>(ei, w, gh, bstart, pk1, E, NB);
  pass2<<<NB, 256, 0, stream>>>(pk1, bstart, pk2, dinv, n);
  val_kernel<<<NB, 256, 0, stream>>>(pk2, bstart, dinv, E, NB);

  // ---- layer 1 ----
  gemm_init<<<nb_gemm, 256, 0, stream>>>(x, W1, b1, dinv, XL16, ACC, n, tiles);
  edge_agg<<<nb_edge, 256, 0, stream>>>(pk2, XL16, ACC, E);
  stats_kernel<<<nb_stats, 256, 0, stream>>>(ACC, stats1, n);
  finalize_stats<<<1, 64, 0, stream>>>(stats1, g1, be1, n);

  // ---- layer 2 ----
  gemm_bn_init<<<nb_gemm, 256, 0, stream>>>(ACC, stats1, al1, W2, b2, dinv, XL16, ACC, n, tiles);
  edge_agg<<<nb_edge, 256, 0, stream>>>(pk2, XL16, ACC, E);
  stats_kernel<<<nb_stats, 256, 0, stream>>>(ACC, stats2, n);
  finalize_stats<<<1, 64, 0, stream>>>(stats2, g2, be2, n);
  bnapply<<<nb_nodes, 256, 0, stream>>>(ACC, stats2, al2, out, n);
}